// Round 2
// baseline (23.766 us; speedup 1.0000x reference)
//
#include <hip/hip_runtime.h>
#include <math.h>

// Problem constants
#define NB 2          // batch
#define NC 30         // classes
#define NH 4          // heads
#define HWA 13600     // 100*136
#define HWB 3400      // 50*68
#define PNUM 20
#define CAP2 256
#define LOGIT_TH -2.1972245773362196  // ln(0.1/0.9): sigmoid(x)>0.1 <=> x>this

struct Ptrs {
    const float* cls[8];   // [h*2 + l]
    const float* reg[8];   // [h*2 + l]
    const float* anc[2];   // [l]
};

struct Sh {
    unsigned long long candU[CAP2];
    unsigned tw[4];
    int cw[4];
    int mcnt;
};

__device__ __forceinline__ unsigned f2key(float x) {
    unsigned u = __float_as_uint(x);
    return (u & 0x80000000u) ? ~u : (u | 0x80000000u);
}

template<int HW, int L>
__device__ __forceinline__ void topk_body(Sh& sh, const Ptrs& p, int bid,
                                          float* __restrict__ topv,
                                          int* __restrict__ topi,
                                          int* __restrict__ cnts) {
    constexpr int N4 = HW / 4;
    constexpr int NV = (N4 + 255) / 256;
    int c = bid % NC; int t = bid / NC;
    int n = t % NB;   int h = t / NB;
    int sid = ((h*2 + L)*NB + n)*NC + c;
    const float* base = p.cls[h*2 + L] + (size_t)(n*NC + c) * HW;
    int tid = threadIdx.x, lane = tid & 63, wv = tid >> 6;

    if (tid == 0) sh.mcnt = 0;

    // Single global pass: values live in registers
    float4 v[NV];
    #pragma unroll
    for (int i = 0; i < NV; ++i) {
        int f = tid + i * 256;
        if (f < N4) v[i] = ((const float4*)base)[f];
    }

    // Per-thread max key + threshold count
    unsigned mk = 0u; int cnt = 0;
    #pragma unroll
    for (int i = 0; i < NV; ++i) {
        int f = tid + i * 256;
        if (f < N4) {
            float xs[4] = {v[i].x, v[i].y, v[i].z, v[i].w};
            #pragma unroll
            for (int j = 0; j < 4; ++j) {
                cnt += ((double)xs[j] > LOGIT_TH);
                unsigned k = f2key(xs[j]);
                mk = (k > mk) ? k : mk;
            }
        }
    }
    // Reduce cnt across wave
    for (int off = 32; off; off >>= 1) cnt += __shfl_down(cnt, off);
    if (lane == 0) sh.cw[wv] = cnt;

    // In-wave bitonic ascending sort of the 64 thread-max keys
    unsigned s = mk;
    #pragma unroll
    for (int k = 2; k <= 64; k <<= 1) {
        #pragma unroll
        for (int j = k >> 1; j > 0; j >>= 1) {
            unsigned o = __shfl_xor(s, j);
            bool up = ((lane & k) == 0);
            bool lower = ((lane & j) == 0);
            s = (up == lower) ? min(s, o) : max(s, o);
        }
    }
    // 20th largest of this wave's maxes = sorted_asc[64 - PNUM]
    unsigned t_w = __shfl(s, 64 - PNUM);
    if (lane == 0) sh.tw[wv] = t_w;
    __syncthreads();

    if (tid == 0) cnts[sid] = sh.cw[0] + sh.cw[1] + sh.cw[2] + sh.cw[3];
    unsigned tk = max(max(sh.tw[0], sh.tw[1]), max(sh.tw[2], sh.tw[3]));

    // Collect candidates: key >= tk  (guaranteed superset of exact top-20)
    #pragma unroll
    for (int i = 0; i < NV; ++i) {
        int f = tid + i * 256;
        if (f < N4) {
            float xs[4] = {v[i].x, v[i].y, v[i].z, v[i].w};
            #pragma unroll
            for (int j = 0; j < 4; ++j) {
                unsigned key = f2key(xs[j]);
                if (key >= tk) {
                    int slot = atomicAdd(&sh.mcnt, 1);
                    if (slot < CAP2) {
                        int eidx = f * 4 + j;
                        sh.candU[slot] = ((unsigned long long)key << 32) |
                                         (unsigned)(~(unsigned)eidx);
                    }
                }
            }
        }
    }
    __syncthreads();

    // Exact rank selection: rank = #{candidates with (key,~idx) strictly greater}
    int M = min(sh.mcnt, CAP2);
    if (tid < M) {
        unsigned long long mu = sh.candU[tid];
        int rank = 0;
        for (int m = 0; m < M; ++m) rank += (sh.candU[m] > mu);
        if (rank < PNUM) {
            unsigned key = (unsigned)(mu >> 32);
            unsigned u = (key & 0x80000000u) ? (key ^ 0x80000000u) : ~key;
            topv[sid * PNUM + rank] = __uint_as_float(u);
            topi[sid * PNUM + rank] = (int)~(unsigned)(mu & 0xFFFFFFFFu);
        }
    }
}

__global__ __launch_bounds__(256) void k_topk_all(Ptrs p, float* __restrict__ topv,
                                                  int* __restrict__ topi,
                                                  int* __restrict__ cnts) {
    __shared__ Sh sh;
    if (blockIdx.x < NH * NB * NC)
        topk_body<HWA, 0>(sh, p, blockIdx.x, topv, topi, cnts);
    else
        topk_body<HWB, 1>(sh, p, blockIdx.x - NH * NB * NC, topv, topi, cnts);
}

// ---------------- Kernel 2: single-gather-round epilogue ----------------
// grid = 240 blocks: bid = (h*2 + n)*30 + c ; block = 64 threads
// All 640 reg gathers + 40 anchor float4s are issued in ONE parallel round
// right after topi lands (addresses depend only on topi, not on pk/box).
__global__ __launch_bounds__(64) void k_out(Ptrs p, const float* __restrict__ topv,
                                            const int* __restrict__ topi,
                                            const int* __restrict__ cnts,
                                            float* __restrict__ out) {
    __shared__ float  tv[2 * PNUM];
    __shared__ int    idxs[2 * PNUM];
    __shared__ float  regv[2 * PNUM][16];
    __shared__ float  ancv[2 * PNUM][4];
    __shared__ double smv[2 * PNUM];
    __shared__ int    val[2 * PNUM];
    __shared__ int    cnt2[2];
    __shared__ int    pk[2];

    int bid = blockIdx.x;
    int c = bid % NC; int t = bid / NC;
    int n = t % NB;   int h = t / NB;
    int tid = threadIdx.x;

    // Round 0: fetch top-20 scores/indices (+counts) — small, L2-resident
    if (tid < 2 * PNUM) {
        int l = tid / PNUM, k = tid % PNUM;
        int sid = ((h*2 + l)*NB + n)*NC + c;
        float x = topv[sid * PNUM + k];
        int  ix = topi[sid * PNUM + k];
        tv[tid] = x;
        idxs[tid] = ix;
    }
    if (tid >= 2 * PNUM && tid < 2 * PNUM + 2) {
        int l = tid - 2 * PNUM;
        int sid = ((h*2 + l)*NB + n)*NC + c;
        cnt2[l] = cnts[sid];
    }
    __syncthreads();

    // Round 1: ONE scattered-gather round for everything.
    // 640 reg values: entry e -> item i = e>>4 (l = i/20), component j = e&15
    #pragma unroll
    for (int e = tid; e < 2 * PNUM * 16; e += 64) {
        int i = e >> 4, j = e & 15;
        int l = i / PNUM;
        int hw = l ? HWB : HWA;
        int pos = idxs[i];
        const float* reg = p.reg[h*2 + l];
        regv[i][j] = reg[((size_t)(n*NC*16 + c*16 + j)) * hw + pos];
    }
    // 40 anchor float4s
    if (tid < 2 * PNUM) {
        int l = tid / PNUM;
        float4 a = ((const float4*)p.anc[l])[idxs[tid]];
        ancv[tid][0] = a.x; ancv[tid][1] = a.y; ancv[tid][2] = a.z; ancv[tid][3] = a.w;
    }
    // Overlap gather latency: sigmoid/validity from own tv (no sync needed —
    // thread tid wrote tv[tid] itself and synced above)
    if (tid < 2 * PNUM) {
        float x = tv[tid];
        int v = ((double)x > LOGIT_TH);
        val[tid] = v;
        smv[tid] = v ? sqrt(1.0 / (1.0 + exp(-(double)x))) : -1e30;
    }
    __syncthreads();

    // Round 2: serial head math (box size from item k=0 of each level)
    if (tid == 0) {
        double best[2], sz[2];
        for (int l = 0; l < 2; ++l) {
            int i0 = l * PNUM;
            best[l] = smv[i0];              // NEG if invalid
            double x1 = ancv[i0][0], y1 = ancv[i0][1], x2 = ancv[i0][2], y2 = ancv[i0][3];
            double wa = x2 - x1, cxa = (x1 + x2) * 0.5;
            double ha = y2 - y1, cya = (y1 + y2) * 0.5;
            double kxmx = -1e300, kxmn = 1e300, kymx = -1e300, kymn = 1e300;
            for (int j = 0; j < 8; ++j) {
                double kx = (double)regv[i0][j]     * wa + cxa;
                double ky = (double)regv[i0][j + 8] * ha + cya;
                kxmx = fmax(kxmx, kx); kxmn = fmin(kxmn, kx);
                kymx = fmax(kymx, ky); kymn = fmin(kymn, ky);
            }
            double s = fmax(kxmx - kxmn, kymx - kymn);
            sz[l] = (best[l] > 0.0) ? s : 0.0;
        }
        int bi = (best[0] >= best[1]) ? 0 : 1;    // argmax, first-max wins
        double box = sz[bi];
        double safe = (box > 0.0) ? box : 1.0;
        double dk0 = log2(safe / 64.0), dk1 = log2(safe / 128.0);
        double e0 = exp(-dk0 * dk0), e1 = exp(-dk1 * dk1);
        double s = e0 + e1;
        int nk0 = (box > 0.0) ? (int)(20.0 * e0 / s + 0.5) : 0;
        int nk1 = (box > 0.0) ? (int)(20.0 * e1 / s + 0.5) : 0;
        pk[0] = min(cnt2[0], nk0);
        pk[1] = min(cnt2[1], nk1);
    }
    __syncthreads();

    // Round 3: write outputs, 40 (l,k) items x 17 floats — all from LDS
    if (tid < 2 * PNUM) {
        int l = tid / PNUM, k = tid % PNUM;
        bool v = (k < pk[l]) && val[tid];
        size_t ob = ((((size_t)((n*NH + h)*NC + c)) * 2 + l) * PNUM + k) * 17;
        float* o = out + ob;
        if (!v) {
            #pragma unroll
            for (int e = 0; e < 17; ++e) o[e] = 0.f;
        } else {
            o[0] = (float)smv[tid];
            double x1 = ancv[tid][0], y1 = ancv[tid][1], x2 = ancv[tid][2], y2 = ancv[tid][3];
            double wa = x2 - x1, cxa = (x1 + x2) * 0.5;
            double ha = y2 - y1, cya = (y1 + y2) * 0.5;
            #pragma unroll
            for (int j = 0; j < 8; ++j)
                o[1 + j] = (float)((double)regv[tid][j] * wa + cxa);
            #pragma unroll
            for (int j = 0; j < 8; ++j)
                o[9 + j] = (float)((double)regv[tid][j + 8] * ha + cya);
        }
    }
}

extern "C" void kernel_launch(void* const* d_in, const int* in_sizes, int n_in,
                              void* d_out, int out_size, void* d_ws, size_t ws_size,
                              hipStream_t stream) {
    Ptrs p;
    for (int h = 0; h < 4; ++h) {
        p.cls[h*2 + 0] = (const float*)d_in[h*4 + 0];
        p.reg[h*2 + 0] = (const float*)d_in[h*4 + 1];
        p.cls[h*2 + 1] = (const float*)d_in[h*4 + 2];
        p.reg[h*2 + 1] = (const float*)d_in[h*4 + 3];
    }
    p.anc[0] = (const float*)d_in[16];
    p.anc[1] = (const float*)d_in[17];

    const int NSER = NH * 2 * NB * NC;  // 480
    float* topv = (float*)d_ws;
    int*   topi = (int*)((char*)d_ws + (size_t)NSER * PNUM * 4);
    int*   cnts = (int*)((char*)d_ws + (size_t)NSER * PNUM * 8);

    k_topk_all<<<NSER, 256, 0, stream>>>(p, topv, topi, cnts);
    k_out<<<NH * NB * NC, 64, 0, stream>>>(p, topv, topi, cnts, (float*)d_out);
}

// Round 3
// 18.761 us; speedup vs baseline: 1.2668x; 1.2668x over previous
//
#include <hip/hip_runtime.h>
#include <hip/hip_bf16.h>
#include <math.h>

// Problem constants
#define NB 2          // batch
#define NC 30         // classes
#define NH 4          // heads
#define HWA 13600     // 100*136
#define HWB 3400      // 50*68
#define PNUM 20
#define CAP2 256
#define LOGIT_TH -2.1972245773362196  // ln(0.1/0.9): sigmoid(x)>0.1 <=> x>this

struct Ptrs {
    const float* cls[8];   // [h*2 + l]
    const float* reg[8];   // [h*2 + l]
    const float* anc[2];   // [l]
};

struct Sh {
    unsigned long long candU[CAP2];
    unsigned tw[4];
    int cw[4];
    int mcnt;
};

__device__ __forceinline__ unsigned f2key(float x) {
    unsigned u = __float_as_uint(x);
    return (u & 0x80000000u) ? ~u : (u | 0x80000000u);
}

template<int HW, int L>
__device__ __forceinline__ void topk_body(Sh& sh, const Ptrs& p, int bid,
                                          float* __restrict__ topv,
                                          int* __restrict__ topi,
                                          int* __restrict__ cnts) {
    constexpr int N4 = HW / 4;
    constexpr int NV = (N4 + 255) / 256;
    int c = bid % NC; int t = bid / NC;
    int n = t % NB;   int h = t / NB;
    int sid = ((h*2 + L)*NB + n)*NC + c;
    const float* base = p.cls[h*2 + L] + (size_t)(n*NC + c) * HW;
    int tid = threadIdx.x, lane = tid & 63, wv = tid >> 6;

    if (tid == 0) sh.mcnt = 0;

    // Single global pass: values live in registers
    float4 v[NV];
    #pragma unroll
    for (int i = 0; i < NV; ++i) {
        int f = tid + i * 256;
        if (f < N4) v[i] = ((const float4*)base)[f];
    }

    // Per-thread max key + threshold count
    unsigned mk = 0u; int cnt = 0;
    #pragma unroll
    for (int i = 0; i < NV; ++i) {
        int f = tid + i * 256;
        if (f < N4) {
            float xs[4] = {v[i].x, v[i].y, v[i].z, v[i].w};
            #pragma unroll
            for (int j = 0; j < 4; ++j) {
                cnt += ((double)xs[j] > LOGIT_TH);
                unsigned k = f2key(xs[j]);
                mk = (k > mk) ? k : mk;
            }
        }
    }
    // Reduce cnt across wave
    for (int off = 32; off; off >>= 1) cnt += __shfl_down(cnt, off);
    if (lane == 0) sh.cw[wv] = cnt;

    // In-wave bitonic ascending sort of the 64 thread-max keys
    unsigned s = mk;
    #pragma unroll
    for (int k = 2; k <= 64; k <<= 1) {
        #pragma unroll
        for (int j = k >> 1; j > 0; j >>= 1) {
            unsigned o = __shfl_xor(s, j);
            bool up = ((lane & k) == 0);
            bool lower = ((lane & j) == 0);
            s = (up == lower) ? min(s, o) : max(s, o);
        }
    }
    // 20th largest of this wave's maxes = sorted_asc[64 - PNUM]
    unsigned t_w = __shfl(s, 64 - PNUM);
    if (lane == 0) sh.tw[wv] = t_w;
    __syncthreads();

    if (tid == 0) cnts[sid] = sh.cw[0] + sh.cw[1] + sh.cw[2] + sh.cw[3];
    unsigned tk = max(max(sh.tw[0], sh.tw[1]), max(sh.tw[2], sh.tw[3]));

    // Collect candidates: key >= tk  (guaranteed superset of exact top-20)
    #pragma unroll
    for (int i = 0; i < NV; ++i) {
        int f = tid + i * 256;
        if (f < N4) {
            float xs[4] = {v[i].x, v[i].y, v[i].z, v[i].w};
            #pragma unroll
            for (int j = 0; j < 4; ++j) {
                unsigned key = f2key(xs[j]);
                if (key >= tk) {
                    int slot = atomicAdd(&sh.mcnt, 1);
                    if (slot < CAP2) {
                        int eidx = f * 4 + j;
                        sh.candU[slot] = ((unsigned long long)key << 32) |
                                         (unsigned)(~(unsigned)eidx);
                    }
                }
            }
        }
    }
    __syncthreads();

    // Exact rank selection: rank = #{candidates with (key,~idx) strictly greater}
    int M = min(sh.mcnt, CAP2);
    if (tid < M) {
        unsigned long long mu = sh.candU[tid];
        int rank = 0;
        for (int m = 0; m < M; ++m) rank += (sh.candU[m] > mu);
        if (rank < PNUM) {
            unsigned key = (unsigned)(mu >> 32);
            unsigned u = (key & 0x80000000u) ? (key ^ 0x80000000u) : ~key;
            topv[sid * PNUM + rank] = __uint_as_float(u);
            topi[sid * PNUM + rank] = (int)~(unsigned)(mu & 0xFFFFFFFFu);
        }
    }
}

__global__ __launch_bounds__(256) void k_topk_all(Ptrs p, float* __restrict__ topv,
                                                  int* __restrict__ topi,
                                                  int* __restrict__ cnts) {
    __shared__ Sh sh;
    if (blockIdx.x < NH * NB * NC)
        topk_body<HWA, 0>(sh, p, blockIdx.x, topv, topi, cnts);
    else
        topk_body<HWB, 1>(sh, p, blockIdx.x - NH * NB * NC, topv, topi, cnts);
}

// ---------------- Kernel 2: heads math + gathered decode + output ----------------
// grid = 240 blocks: bid = (h*2 + n)*30 + c ; block = 64 threads
__global__ __launch_bounds__(64) void k_out(Ptrs p, const float* __restrict__ topv,
                                            const int* __restrict__ topi,
                                            const int* __restrict__ cnts,
                                            float* __restrict__ out) {
    __shared__ double sm[2 * PNUM];
    __shared__ int    idxs[2 * PNUM];
    __shared__ int    val[2 * PNUM];
    __shared__ double k16[2][16];
    __shared__ int    pk[2];

    int bid = blockIdx.x;
    int c = bid % NC; int t = bid / NC;
    int n = t % NB;   int h = t / NB;
    int tid = threadIdx.x;

    if (tid < 2 * PNUM) {
        int l = tid / PNUM, k = tid % PNUM;
        int sid = ((h*2 + l)*NB + n)*NC + c;
        float x = topv[sid * PNUM + k];
        int  ix = topi[sid * PNUM + k];
        idxs[tid] = ix;
        int v = ((double)x > LOGIT_TH);
        val[tid] = v;
        sm[tid] = v ? sqrt(1.0 / (1.0 + exp(-(double)x))) : -1e30;
    }
    __syncthreads();

    // gather top-1 box (for size), 32 threads: (l, j)
    if (tid < 32) {
        int l = tid / 16, j = tid % 16;
        int hw = l ? HWB : HWA;
        int pos = idxs[l * PNUM];           // argmax index
        const float* reg = p.reg[h*2 + l];
        double r = (double)reg[((size_t)(n*NC*16 + c*16 + j)) * hw + pos];
        const float* anc = p.anc[l];
        double x1 = anc[pos*4+0], y1 = anc[pos*4+1], x2 = anc[pos*4+2], y2 = anc[pos*4+3];
        double kv;
        if (j < 8) kv = r * (x2 - x1) + (x1 + x2) * 0.5;
        else       kv = r * (y2 - y1) + (y1 + y2) * 0.5;
        k16[l][j] = kv;
    }
    __syncthreads();

    if (tid == 0) {
        double best[2], sz[2];
        for (int l = 0; l < 2; ++l) {
            best[l] = sm[l * PNUM];         // NEG if invalid
            double kxmx = -1e300, kxmn = 1e300, kymx = -1e300, kymn = 1e300;
            for (int j = 0; j < 8; ++j) {
                double kx = k16[l][j], ky = k16[l][j + 8];
                kxmx = fmax(kxmx, kx); kxmn = fmin(kxmn, kx);
                kymx = fmax(kymx, ky); kymn = fmin(kymn, ky);
            }
            double s = fmax(kxmx - kxmn, kymx - kymn);
            sz[l] = (best[l] > 0.0) ? s : 0.0;
        }
        int bi = (best[0] >= best[1]) ? 0 : 1;    // argmax, first-max wins
        double box = sz[bi];
        double safe = (box > 0.0) ? box : 1.0;
        double dk0 = log2(safe / 64.0), dk1 = log2(safe / 128.0);
        double e0 = exp(-dk0 * dk0), e1 = exp(-dk1 * dk1);
        double s = e0 + e1;
        int nk0 = (box > 0.0) ? (int)(20.0 * e0 / s + 0.5) : 0;
        int nk1 = (box > 0.0) ? (int)(20.0 * e1 / s + 0.5) : 0;
        int sid0 = ((h*2 + 0)*NB + n)*NC + c;
        int sid1 = ((h*2 + 1)*NB + n)*NC + c;
        pk[0] = min(cnts[sid0], nk0);
        pk[1] = min(cnts[sid1], nk1);
    }
    __syncthreads();

    // write outputs: 40 (l,k) items, 17 floats each
    if (tid < 2 * PNUM) {
        int l = tid / PNUM, k = tid % PNUM;
        int hw = l ? HWB : HWA;
        bool v = (k < pk[l]) && val[tid];
        size_t ob = ((((size_t)((n*NH + h)*NC + c)) * 2 + l) * PNUM + k) * 17;
        float* o = out + ob;
        if (!v) {
            #pragma unroll
            for (int e = 0; e < 17; ++e) o[e] = 0.f;
        } else {
            o[0] = (float)sm[tid];
            int pos = idxs[tid];
            const float* reg = p.reg[h*2 + l];
            const float* anc = p.anc[l];
            double x1 = anc[pos*4+0], y1 = anc[pos*4+1], x2 = anc[pos*4+2], y2 = anc[pos*4+3];
            double wa = x2 - x1, cxa = (x1 + x2) * 0.5;
            double ha = y2 - y1, cya = (y1 + y2) * 0.5;
            size_t rb = ((size_t)(n*NC*16 + c*16)) * hw + pos;
            #pragma unroll
            for (int j = 0; j < 8; ++j)
                o[1 + j] = (float)((double)reg[rb + (size_t)j * hw] * wa + cxa);
            #pragma unroll
            for (int j = 0; j < 8; ++j)
                o[9 + j] = (float)((double)reg[rb + (size_t)(j + 8) * hw] * ha + cya);
        }
    }
}

extern "C" void kernel_launch(void* const* d_in, const int* in_sizes, int n_in,
                              void* d_out, int out_size, void* d_ws, size_t ws_size,
                              hipStream_t stream) {
    Ptrs p;
    for (int h = 0; h < 4; ++h) {
        p.cls[h*2 + 0] = (const float*)d_in[h*4 + 0];
        p.reg[h*2 + 0] = (const float*)d_in[h*4 + 1];
        p.cls[h*2 + 1] = (const float*)d_in[h*4 + 2];
        p.reg[h*2 + 1] = (const float*)d_in[h*4 + 3];
    }
    p.anc[0] = (const float*)d_in[16];
    p.anc[1] = (const float*)d_in[17];

    const int NSER = NH * 2 * NB * NC;  // 480
    float* topv = (float*)d_ws;
    int*   topi = (int*)((char*)d_ws + (size_t)NSER * PNUM * 4);
    int*   cnts = (int*)((char*)d_ws + (size_t)NSER * PNUM * 8);

    k_topk_all<<<NSER, 256, 0, stream>>>(p, topv, topi, cnts);
    k_out<<<NH * NB * NC, 64, 0, stream>>>(p, topv, topi, cnts, (float*)d_out);
}